// Round 14
// baseline (89.122 us; speedup 1.0000x reference)
//
#include <hip/hip_runtime.h>
#include <hip/hip_bf16.h>

#define DIM 32
#define LOG_NPB 7
#define NPB 128              // nodes per bucket
#define CAP 4096             // edge capacity per bucket (avg ~2046)
#define NBINS 800            // >= ceil(100000/128)=782
#define EPB 12288            // edges per scatter block (48 KB LDS stage)
#define EPT 12               // edges per thread in scatter (EPB/1024)

// ---------------------------------------------------------------------------
// Kernel 1: out = x @ W2^T + b2 (fp32) ;  y = x @ W1^T (bf16 packed).
// Block 0 also inits bucket cursors (absolute: cursor[b] = b*CAP).
// ---------------------------------------------------------------------------
__global__ __launch_bounds__(256) void fused_lin_kernel(
    const float* __restrict__ x,
    const float* __restrict__ W1,
    const float* __restrict__ W2,
    const float* __restrict__ b2,
    float* __restrict__ out,
    unsigned* __restrict__ y32,
    int* __restrict__ cursor, int nb,
    int n_nodes)
{
    __shared__ float W1s[DIM][DIM];
    __shared__ float W2s[DIM][DIM];
    __shared__ float b2s[DIM];
    __shared__ float xs[8][DIM];

    const int t = threadIdx.x;

    if (blockIdx.x == 0) {
        for (int i = t; i < nb; i += 256) cursor[i] = i * CAP;
    }

    for (int i = t; i < DIM * DIM; i += 256) {
        int c = i >> 5, k = i & 31;
        W1s[k][c] = W1[i];
        W2s[k][c] = W2[i];
    }
    if (t < DIM) b2s[t] = b2[t];

    const int r = t >> 5;
    const int c = t & 31;
    const int ntiles = (n_nodes + 7) >> 3;

    for (int tile = blockIdx.x; tile < ntiles; tile += gridDim.x) {
        const int row = tile * 8 + r;
        __syncthreads();
        if (row < n_nodes) xs[r][c] = x[(long)row * DIM + c];
        __syncthreads();
        if (row < n_nodes) {
            float a2 = b2s[c];
            float a1 = 0.0f;
            #pragma unroll
            for (int k = 0; k < DIM; ++k) {
                float xv = xs[r][k];
                a2 += xv * W2s[k][c];
                a1 += xv * W1s[k][c];
            }
            out[(long)row * DIM + c] = a2;
            float hi = __shfl_down(a1, 1);
            if ((c & 1) == 0) {
                __hip_bfloat16 blo = __float2bfloat16(a1);
                __hip_bfloat16 bhi = __float2bfloat16(hi);
                unsigned pack = ((unsigned)(*(unsigned short*)&bhi) << 16)
                              | (unsigned)(*(unsigned short*)&blo);
                y32[(size_t)row * 16 + (c >> 1)] = pack;
            }
        }
    }
}

// ---------------------------------------------------------------------------
// Pass 1: bucket scatter via per-block counting sort in LDS.
// hist -> scan -> global bases -> LDS-stage in bucket order -> COALESCED
// write-out (wave w copies bins w, w+16, ...). Write transactions drop from
// ~1 per edge to ~1-2 per (block,bin).
// ---------------------------------------------------------------------------
__global__ __launch_bounds__(1024) void bucket_scatter_kernel(
    const int* __restrict__ src, const int* __restrict__ dst,
    int* __restrict__ cursor, unsigned* __restrict__ bedges, int nE)
{
    __shared__ unsigned stage[EPB];     // 48 KB: packed edges in bin-sorted order
    __shared__ int cnt[NBINS];          // per-bin count
    __shared__ int ex[NBINS];           // per-bin exclusive start (LDS order)
    __shared__ int gbase[NBINS];        // per-bin global base
    __shared__ int scanbuf[1024];       // scan scratch; reused as cur[] in phase D

    const int t = threadIdx.x;
    const long blockStart = (long)blockIdx.x * EPB;

    // phase 0: zero hist
    for (int i = t; i < NBINS; i += 1024) cnt[i] = 0;
    __syncthreads();

    // phase A: histogram over dst buckets
    #pragma unroll
    for (int i = 0; i < EPT; ++i) {
        long e = blockStart + (long)i * 1024 + t;
        if (e < nE) atomicAdd(&cnt[dst[e] >> LOG_NPB], 1);
    }
    __syncthreads();

    // phase B: exclusive scan of cnt -> ex  (Hillis-Steele, 1024 wide)
    int v = (t < NBINS) ? cnt[t] : 0;
    scanbuf[t] = v;
    __syncthreads();
    for (int off = 1; off < 1024; off <<= 1) {
        int add = (t >= off) ? scanbuf[t - off] : 0;
        __syncthreads();
        scanbuf[t] += add;
        __syncthreads();
    }
    if (t < NBINS) ex[t] = scanbuf[t] - v;
    __syncthreads();

    // phase C: global base per bin (one parallel atomic round) + re-zero cur
    for (int b = t; b < NBINS; b += 1024) {
        int c = cnt[b];
        if (c > 0) gbase[b] = atomicAdd(&cursor[b], c);
    }
    scanbuf[t] = 0;                      // scanbuf now serves as cur[]
    __syncthreads();

    // phase D: re-read edges, rank via LDS atomic, stage in bin-sorted order
    #pragma unroll
    for (int i = 0; i < EPT; ++i) {
        long e = blockStart + (long)i * 1024 + t;
        if (e < nE) {
            int es = src[e];
            int ed = dst[e];
            int b  = ed >> LOG_NPB;
            int r  = atomicAdd(&scanbuf[b], 1);
            stage[ex[b] + r] = ((unsigned)es << LOG_NPB) | (unsigned)(ed & (NPB - 1));
        }
    }
    __syncthreads();

    // phase E: coalesced write-out, one wave per bin
    const int wv   = t >> 6;
    const int lane = t & 63;
    for (int b = wv; b < NBINS; b += 16) {
        int c = cnt[b];
        if (c == 0) continue;
        int lbase = ex[b];
        int gb    = gbase[b];
        int cmax  = (b + 1) * CAP - gb;  // capacity guard (never trips in practice)
        if (cmax < 0) cmax = 0;
        if (c > cmax) c = cmax;
        for (int j = lane; j < c; j += 64)
            bedges[gb + j] = stage[lbase + j];
    }
}

// ---------------------------------------------------------------------------
// Pass 2 (fused): per-bucket LDS sort, then software-pipelined gather.
// (unchanged from round 13)
// ---------------------------------------------------------------------------
__global__ __launch_bounds__(512) void sort_gather_kernel(
    const int* __restrict__ cursor, const unsigned* __restrict__ bedges,
    const unsigned short* __restrict__ yb,
    float* __restrict__ out, int n_nodes)
{
    __shared__ unsigned ent[CAP];      // 16 KB raw entries
    __shared__ unsigned sorted[CAP];   // 16 KB src ids sorted by local dst
    __shared__ int cnt[NPB];
    __shared__ int ex[NPB];
    __shared__ int cur[NPB];

    const int b = blockIdx.x;
    const int t = threadIdx.x;
    const int start = b * CAP;
    int n = cursor[b] - start;
    if (n > CAP) n = CAP;
    if (n < 0) n = 0;

    if (t < NPB) { cnt[t] = 0; cur[t] = 0; }
    __syncthreads();

    for (int i = t; i < n; i += 512) {
        unsigned e = bedges[start + i];
        ent[i] = e;
        atomicAdd(&cnt[e & (NPB - 1)], 1);
    }
    __syncthreads();

    if (t < NPB) ex[t] = cnt[t];
    __syncthreads();
    for (int off = 1; off < NPB; off <<= 1) {
        int add = 0;
        if (t < NPB && t >= off) add = ex[t - off];
        __syncthreads();
        if (t < NPB) ex[t] += add;
        __syncthreads();
    }
    if (t < NPB) ex[t] -= cnt[t];
    __syncthreads();

    for (int i = t; i < n; i += 512) {
        unsigned e = ent[i];
        int bin = (int)(e & (NPB - 1));
        int r = atomicAdd(&cur[bin], 1);
        sorted[ex[bin] + r] = e >> LOG_NPB;
    }
    __syncthreads();

    // ---- pipelined gather phase ----
    const int wv   = t >> 6;      // wave 0..7
    const int lane = t & 63;
    const int slot = lane >> 3;   // 0..7: edge slot
    const int li   = lane & 7;    // dims li*4..li*4+3

    int ln   = wv;
    int node = b * NPB + ln;
    if (node >= n_nodes) return;

    int st = ex[ln];
    int d  = cnt[ln];
    int s[4];
    #pragma unroll
    for (int k = 0; k < 4; ++k) {
        int e = slot + 8 * k;
        int idx = (e < d) ? e : (d > 0 ? d - 1 : 0);
        s[k] = (int)sorted[(d > 0 ? st : 0) + idx];
    }
    float4 o = make_float4(0.f, 0.f, 0.f, 0.f);
    if (slot == 0) o = ((const float4*)(out + ((size_t)node << 5)))[li];

    while (true) {
        ushort4 u[4];
        #pragma unroll
        for (int k = 0; k < 4; ++k) {
            if (8 * k < d)    // wave-uniform
                u[k] = *(const ushort4*)(yb + ((size_t)s[k] << 5) + (li << 2));
        }

        const int ln_n   = ln + 8;
        const int node_n = node + 8;
        const bool have_n = (ln_n < NPB) && (node_n < n_nodes);
        int st_n = 0, d_n = 0;
        int sn[4];
        float4 o_n = make_float4(0.f, 0.f, 0.f, 0.f);
        if (have_n) {
            st_n = ex[ln_n];
            d_n  = cnt[ln_n];
            #pragma unroll
            for (int k = 0; k < 4; ++k) {
                int e = slot + 8 * k;
                int idx = (e < d_n) ? e : (d_n > 0 ? d_n - 1 : 0);
                sn[k] = (int)sorted[(d_n > 0 ? st_n : 0) + idx];
            }
            if (slot == 0) o_n = ((const float4*)(out + ((size_t)node_n << 5)))[li];
        }

        float a0 = 0.f, a1 = 0.f, a2 = 0.f, a3 = 0.f;
        #pragma unroll
        for (int k = 0; k < 4; ++k) {
            if (8 * k < d) {   // wave-uniform
                const bool v = (slot + 8 * k) < d;
                a0 += v ? __uint_as_float((unsigned)u[k].x << 16) : 0.f;
                a1 += v ? __uint_as_float((unsigned)u[k].y << 16) : 0.f;
                a2 += v ? __uint_as_float((unsigned)u[k].z << 16) : 0.f;
                a3 += v ? __uint_as_float((unsigned)u[k].w << 16) : 0.f;
            }
        }
        for (int e0 = 32 + slot; e0 < d; e0 += 8) {
            int ss = (int)sorted[st + e0];
            ushort4 uu = *(const ushort4*)(yb + ((size_t)ss << 5) + (li << 2));
            a0 += __uint_as_float((unsigned)uu.x << 16);
            a1 += __uint_as_float((unsigned)uu.y << 16);
            a2 += __uint_as_float((unsigned)uu.z << 16);
            a3 += __uint_as_float((unsigned)uu.w << 16);
        }

        #pragma unroll
        for (int m = 8; m < 64; m <<= 1) {
            a0 += __shfl_xor(a0, m);
            a1 += __shfl_xor(a1, m);
            a2 += __shfl_xor(a2, m);
            a3 += __shfl_xor(a3, m);
        }

        if (slot == 0 && d > 0) {
            float4 w;
            w.x = o.x + a0; w.y = o.y + a1; w.z = o.z + a2; w.w = o.w + a3;
            ((float4*)(out + ((size_t)node << 5)))[li] = w;
        }

        if (!have_n) break;
        ln = ln_n; node = node_n; st = st_n; d = d_n;
        s[0] = sn[0]; s[1] = sn[1]; s[2] = sn[2]; s[3] = sn[3];
        o = o_n;
    }
}

extern "C" void kernel_launch(void* const* d_in, const int* in_sizes, int n_in,
                              void* d_out, int out_size, void* d_ws, size_t ws_size,
                              hipStream_t stream) {
    const float* x  = (const float*)d_in[0];
    const float* W1 = (const float*)d_in[1];
    const float* W2 = (const float*)d_in[2];
    const float* b2 = (const float*)d_in[3];
    const int*   ei = (const int*)d_in[4];

    const int n_nodes = in_sizes[0] / DIM;   // 100000
    const int n_edges = in_sizes[4] / 2;     // 1,600,000
    const int* src = ei;
    const int* dst = ei + n_edges;
    float* out = (float*)d_out;

    const int nb = (n_nodes + NPB - 1) / NPB;    // 782

    char* basep = (char*)d_ws;
    size_t off = 0;
    auto alloc = [&](size_t bytes) {
        char* p = basep + off;
        off = (off + bytes + 255) & ~(size_t)255;
        return p;
    };
    unsigned* y32    = (unsigned*)alloc((size_t)n_nodes * DIM * sizeof(unsigned short));
    int*      cursor = (int*)     alloc((size_t)nb * sizeof(int));
    unsigned* bedges = (unsigned*)alloc((size_t)nb * CAP * sizeof(unsigned));
    (void)ws_size;

    fused_lin_kernel<<<1024, 256, 0, stream>>>(x, W1, W2, b2, out, y32, cursor, nb, n_nodes);
    bucket_scatter_kernel<<<(n_edges + EPB - 1) / EPB, 1024, 0, stream>>>(src, dst, cursor, bedges, n_edges);
    sort_gather_kernel<<<nb, 512, 0, stream>>>(cursor, bedges, (const unsigned short*)y32, out, n_nodes);
}

// Round 15
// 82.816 us; speedup vs baseline: 1.0762x; 1.0762x over previous
//
#include <hip/hip_runtime.h>
#include <hip/hip_bf16.h>

#define DIM 32
#define LOG_NPB 7
#define NPB 128              // nodes per bucket
#define CAP 4096             // edge capacity per bucket (avg ~2046)
#define NBINS 800            // >= ceil(100000/128)=782
#define EPB 4096             // edges per scatter block
#define EPT 4                // edges per thread in scatter (EPB/1024)

// ---------------------------------------------------------------------------
// Kernel 1: out = x @ W2^T + b2 (fp32) ;  y = x @ W1^T (bf16 packed).
// Block 0 also inits bucket cursors (absolute: cursor[b] = b*CAP).
// ---------------------------------------------------------------------------
__global__ __launch_bounds__(256) void fused_lin_kernel(
    const float* __restrict__ x,
    const float* __restrict__ W1,
    const float* __restrict__ W2,
    const float* __restrict__ b2,
    float* __restrict__ out,
    unsigned* __restrict__ y32,
    int* __restrict__ cursor, int nb,
    int n_nodes)
{
    __shared__ float W1s[DIM][DIM];
    __shared__ float W2s[DIM][DIM];
    __shared__ float b2s[DIM];
    __shared__ float xs[8][DIM];

    const int t = threadIdx.x;

    if (blockIdx.x == 0) {
        for (int i = t; i < nb; i += 256) cursor[i] = i * CAP;
    }

    for (int i = t; i < DIM * DIM; i += 256) {
        int c = i >> 5, k = i & 31;
        W1s[k][c] = W1[i];
        W2s[k][c] = W2[i];
    }
    if (t < DIM) b2s[t] = b2[t];

    const int r = t >> 5;
    const int c = t & 31;
    const int ntiles = (n_nodes + 7) >> 3;

    for (int tile = blockIdx.x; tile < ntiles; tile += gridDim.x) {
        const int row = tile * 8 + r;
        __syncthreads();
        if (row < n_nodes) xs[r][c] = x[(long)row * DIM + c];
        __syncthreads();
        if (row < n_nodes) {
            float a2 = b2s[c];
            float a1 = 0.0f;
            #pragma unroll
            for (int k = 0; k < DIM; ++k) {
                float xv = xs[r][k];
                a2 += xv * W2s[k][c];
                a1 += xv * W1s[k][c];
            }
            out[(long)row * DIM + c] = a2;
            float hi = __shfl_down(a1, 1);
            if ((c & 1) == 0) {
                __hip_bfloat16 blo = __float2bfloat16(a1);
                __hip_bfloat16 bhi = __float2bfloat16(hi);
                unsigned pack = ((unsigned)(*(unsigned short*)&bhi) << 16)
                              | (unsigned)(*(unsigned short*)&blo);
                y32[(size_t)row * 16 + (c >> 1)] = pack;
            }
        }
    }
}

// ---------------------------------------------------------------------------
// Pass 1: bucket scatter. 391 blocks x 1024 threads (24 waves/CU in flight,
// 4x round-13's TLP). Rank merged into the histogram atomic (r13 trick).
// ---------------------------------------------------------------------------
__global__ __launch_bounds__(1024) void bucket_scatter_kernel(
    const int* __restrict__ src, const int* __restrict__ dst,
    int* __restrict__ cursor, unsigned* __restrict__ bedges, int nE)
{
    __shared__ int cnt[NBINS];
    __shared__ int base[NBINS];

    const int t = threadIdx.x;
    const long blockStart = (long)blockIdx.x * EPB;

    for (int i = t; i < NBINS; i += 1024) cnt[i] = 0;
    __syncthreads();

    int es[EPT], ed[EPT], rk[EPT];
    #pragma unroll
    for (int i = 0; i < EPT; ++i) {
        long e = blockStart + (long)i * 1024 + t;
        if (e < nE) { es[i] = src[e]; ed[i] = dst[e]; }
        else        { es[i] = -1;     ed[i] = 0;      }
    }
    #pragma unroll
    for (int i = 0; i < EPT; ++i) {
        if (es[i] >= 0) rk[i] = atomicAdd(&cnt[ed[i] >> LOG_NPB], 1);
    }
    __syncthreads();

    for (int i = t; i < NBINS; i += 1024) {
        int c = cnt[i];
        if (c > 0) base[i] = atomicAdd(&cursor[i], c);
    }
    __syncthreads();

    #pragma unroll
    for (int i = 0; i < EPT; ++i) {
        if (es[i] >= 0) {
            int b = ed[i] >> LOG_NPB;
            int p = base[b] + rk[i];
            if (p < (b + 1) * CAP)
                bedges[p] = ((unsigned)es[i] << LOG_NPB) | (unsigned)(ed[i] & (NPB - 1));
        }
    }
}

// ---------------------------------------------------------------------------
// Pass 2 (fused): per-bucket LDS sort, then software-pipelined gather.
// (unchanged from round 13)
// ---------------------------------------------------------------------------
__global__ __launch_bounds__(512) void sort_gather_kernel(
    const int* __restrict__ cursor, const unsigned* __restrict__ bedges,
    const unsigned short* __restrict__ yb,
    float* __restrict__ out, int n_nodes)
{
    __shared__ unsigned ent[CAP];      // 16 KB raw entries
    __shared__ unsigned sorted[CAP];   // 16 KB src ids sorted by local dst
    __shared__ int cnt[NPB];
    __shared__ int ex[NPB];
    __shared__ int cur[NPB];

    const int b = blockIdx.x;
    const int t = threadIdx.x;
    const int start = b * CAP;
    int n = cursor[b] - start;
    if (n > CAP) n = CAP;
    if (n < 0) n = 0;

    if (t < NPB) { cnt[t] = 0; cur[t] = 0; }
    __syncthreads();

    for (int i = t; i < n; i += 512) {
        unsigned e = bedges[start + i];
        ent[i] = e;
        atomicAdd(&cnt[e & (NPB - 1)], 1);
    }
    __syncthreads();

    if (t < NPB) ex[t] = cnt[t];
    __syncthreads();
    for (int off = 1; off < NPB; off <<= 1) {
        int add = 0;
        if (t < NPB && t >= off) add = ex[t - off];
        __syncthreads();
        if (t < NPB) ex[t] += add;
        __syncthreads();
    }
    if (t < NPB) ex[t] -= cnt[t];
    __syncthreads();

    for (int i = t; i < n; i += 512) {
        unsigned e = ent[i];
        int bin = (int)(e & (NPB - 1));
        int r = atomicAdd(&cur[bin], 1);
        sorted[ex[bin] + r] = e >> LOG_NPB;
    }
    __syncthreads();

    // ---- pipelined gather phase ----
    const int wv   = t >> 6;      // wave 0..7
    const int lane = t & 63;
    const int slot = lane >> 3;   // 0..7: edge slot
    const int li   = lane & 7;    // dims li*4..li*4+3

    int ln   = wv;
    int node = b * NPB + ln;
    if (node >= n_nodes) return;

    int st = ex[ln];
    int d  = cnt[ln];
    int s[4];
    #pragma unroll
    for (int k = 0; k < 4; ++k) {
        int e = slot + 8 * k;
        int idx = (e < d) ? e : (d > 0 ? d - 1 : 0);
        s[k] = (int)sorted[(d > 0 ? st : 0) + idx];
    }
    float4 o = make_float4(0.f, 0.f, 0.f, 0.f);
    if (slot == 0) o = ((const float4*)(out + ((size_t)node << 5)))[li];

    while (true) {
        ushort4 u[4];
        #pragma unroll
        for (int k = 0; k < 4; ++k) {
            if (8 * k < d)    // wave-uniform
                u[k] = *(const ushort4*)(yb + ((size_t)s[k] << 5) + (li << 2));
        }

        const int ln_n   = ln + 8;
        const int node_n = node + 8;
        const bool have_n = (ln_n < NPB) && (node_n < n_nodes);
        int st_n = 0, d_n = 0;
        int sn[4];
        float4 o_n = make_float4(0.f, 0.f, 0.f, 0.f);
        if (have_n) {
            st_n = ex[ln_n];
            d_n  = cnt[ln_n];
            #pragma unroll
            for (int k = 0; k < 4; ++k) {
                int e = slot + 8 * k;
                int idx = (e < d_n) ? e : (d_n > 0 ? d_n - 1 : 0);
                sn[k] = (int)sorted[(d_n > 0 ? st_n : 0) + idx];
            }
            if (slot == 0) o_n = ((const float4*)(out + ((size_t)node_n << 5)))[li];
        }

        float a0 = 0.f, a1 = 0.f, a2 = 0.f, a3 = 0.f;
        #pragma unroll
        for (int k = 0; k < 4; ++k) {
            if (8 * k < d) {   // wave-uniform
                const bool v = (slot + 8 * k) < d;
                a0 += v ? __uint_as_float((unsigned)u[k].x << 16) : 0.f;
                a1 += v ? __uint_as_float((unsigned)u[k].y << 16) : 0.f;
                a2 += v ? __uint_as_float((unsigned)u[k].z << 16) : 0.f;
                a3 += v ? __uint_as_float((unsigned)u[k].w << 16) : 0.f;
            }
        }
        for (int e0 = 32 + slot; e0 < d; e0 += 8) {
            int ss = (int)sorted[st + e0];
            ushort4 uu = *(const ushort4*)(yb + ((size_t)ss << 5) + (li << 2));
            a0 += __uint_as_float((unsigned)uu.x << 16);
            a1 += __uint_as_float((unsigned)uu.y << 16);
            a2 += __uint_as_float((unsigned)uu.z << 16);
            a3 += __uint_as_float((unsigned)uu.w << 16);
        }

        #pragma unroll
        for (int m = 8; m < 64; m <<= 1) {
            a0 += __shfl_xor(a0, m);
            a1 += __shfl_xor(a1, m);
            a2 += __shfl_xor(a2, m);
            a3 += __shfl_xor(a3, m);
        }

        if (slot == 0 && d > 0) {
            float4 w;
            w.x = o.x + a0; w.y = o.y + a1; w.z = o.z + a2; w.w = o.w + a3;
            ((float4*)(out + ((size_t)node << 5)))[li] = w;
        }

        if (!have_n) break;
        ln = ln_n; node = node_n; st = st_n; d = d_n;
        s[0] = sn[0]; s[1] = sn[1]; s[2] = sn[2]; s[3] = sn[3];
        o = o_n;
    }
}

extern "C" void kernel_launch(void* const* d_in, const int* in_sizes, int n_in,
                              void* d_out, int out_size, void* d_ws, size_t ws_size,
                              hipStream_t stream) {
    const float* x  = (const float*)d_in[0];
    const float* W1 = (const float*)d_in[1];
    const float* W2 = (const float*)d_in[2];
    const float* b2 = (const float*)d_in[3];
    const int*   ei = (const int*)d_in[4];

    const int n_nodes = in_sizes[0] / DIM;   // 100000
    const int n_edges = in_sizes[4] / 2;     // 1,600,000
    const int* src = ei;
    const int* dst = ei + n_edges;
    float* out = (float*)d_out;

    const int nb = (n_nodes + NPB - 1) / NPB;    // 782

    char* basep = (char*)d_ws;
    size_t off = 0;
    auto alloc = [&](size_t bytes) {
        char* p = basep + off;
        off = (off + bytes + 255) & ~(size_t)255;
        return p;
    };
    unsigned* y32    = (unsigned*)alloc((size_t)n_nodes * DIM * sizeof(unsigned short));
    int*      cursor = (int*)     alloc((size_t)nb * sizeof(int));
    unsigned* bedges = (unsigned*)alloc((size_t)nb * CAP * sizeof(unsigned));
    (void)ws_size;

    fused_lin_kernel<<<1024, 256, 0, stream>>>(x, W1, W2, b2, out, y32, cursor, nb, n_nodes);
    bucket_scatter_kernel<<<(n_edges + EPB - 1) / EPB, 1024, 0, stream>>>(src, dst, cursor, bedges, n_edges);
    sort_gather_kernel<<<nb, 512, 0, stream>>>(cursor, bedges, (const unsigned short*)y32, out, n_nodes);
}

// Round 16
// 82.212 us; speedup vs baseline: 1.0841x; 1.0073x over previous
//
#include <hip/hip_runtime.h>
#include <hip/hip_bf16.h>

#define DIM 32
#define LOG_NPB 7
#define NPB 128              // nodes per bucket
#define CAP 4096             // edge capacity per bucket (avg ~2046)
#define NBINS 800            // >= ceil(100000/128)=782
#define EPB 4096             // edges per scatter block
#define EPT 4                // edges per thread in scatter (EPB/1024)

// ---------------------------------------------------------------------------
// Kernel 1: out = x @ W2^T + b2 (fp32) ;  y = x @ W1^T (bf16 packed).
// Block 0 also inits bucket cursors (absolute: cursor[b] = b*CAP).
// ---------------------------------------------------------------------------
__global__ __launch_bounds__(256) void fused_lin_kernel(
    const float* __restrict__ x,
    const float* __restrict__ W1,
    const float* __restrict__ W2,
    const float* __restrict__ b2,
    float* __restrict__ out,
    unsigned* __restrict__ y32,
    int* __restrict__ cursor, int nb,
    int n_nodes)
{
    __shared__ float W1s[DIM][DIM];
    __shared__ float W2s[DIM][DIM];
    __shared__ float b2s[DIM];
    __shared__ float xs[8][DIM];

    const int t = threadIdx.x;

    if (blockIdx.x == 0) {
        for (int i = t; i < nb; i += 256) cursor[i] = i * CAP;
    }

    for (int i = t; i < DIM * DIM; i += 256) {
        int c = i >> 5, k = i & 31;
        W1s[k][c] = W1[i];
        W2s[k][c] = W2[i];
    }
    if (t < DIM) b2s[t] = b2[t];

    const int r = t >> 5;
    const int c = t & 31;
    const int ntiles = (n_nodes + 7) >> 3;

    for (int tile = blockIdx.x; tile < ntiles; tile += gridDim.x) {
        const int row = tile * 8 + r;
        __syncthreads();
        if (row < n_nodes) xs[r][c] = x[(long)row * DIM + c];
        __syncthreads();
        if (row < n_nodes) {
            float a2 = b2s[c];
            float a1 = 0.0f;
            #pragma unroll
            for (int k = 0; k < DIM; ++k) {
                float xv = xs[r][k];
                a2 += xv * W2s[k][c];
                a1 += xv * W1s[k][c];
            }
            out[(long)row * DIM + c] = a2;
            float hi = __shfl_down(a1, 1);
            if ((c & 1) == 0) {
                __hip_bfloat16 blo = __float2bfloat16(a1);
                __hip_bfloat16 bhi = __float2bfloat16(hi);
                unsigned pack = ((unsigned)(*(unsigned short*)&bhi) << 16)
                              | (unsigned)(*(unsigned short*)&blo);
                y32[(size_t)row * 16 + (c >> 1)] = pack;
            }
        }
    }
}

// ---------------------------------------------------------------------------
// Pass 1: bucket scatter, counting-sort-staged for coalesced write-out.
// 391 blocks x 1024 threads, 29.6 KB LDS (2 blocks/CU, wave-limited).
// Single edge read; rank merged into histogram atomic; gbase atomics
// overlap the scan; 16-lane groups copy whole bins contiguously.
// ---------------------------------------------------------------------------
__global__ __launch_bounds__(1024) void bucket_scatter_kernel(
    const int* __restrict__ src, const int* __restrict__ dst,
    int* __restrict__ cursor, unsigned* __restrict__ bedges, int nE)
{
    __shared__ unsigned stage[EPB];     // 16 KB, edges in bin-sorted order
    __shared__ int cnt[NBINS];
    __shared__ int ex[NBINS];
    __shared__ int gbase[NBINS];
    __shared__ int scanbuf[1024];

    const int t = threadIdx.x;
    const long blockStart = (long)blockIdx.x * EPB;

    for (int i = t; i < NBINS; i += 1024) cnt[i] = 0;
    __syncthreads();

    // single read + rank-merged histogram
    int bn[EPT], rk[EPT];
    unsigned pk[EPT];
    #pragma unroll
    for (int i = 0; i < EPT; ++i) {
        long e = blockStart + (long)i * 1024 + t;
        if (e < nE) {
            int s  = src[e];
            int dd = dst[e];
            bn[i] = dd >> LOG_NPB;
            pk[i] = ((unsigned)s << LOG_NPB) | (unsigned)(dd & (NPB - 1));
            rk[i] = atomicAdd(&cnt[bn[i]], 1);
        } else bn[i] = -1;
    }
    __syncthreads();

    // global bases (independent of the scan; no barrier needed between them)
    for (int b = t; b < NBINS; b += 1024) {
        int c = cnt[b];
        if (c > 0) gbase[b] = atomicAdd(&cursor[b], c);
    }

    // exclusive scan of cnt -> ex (Hillis-Steele over 1024 lanes)
    int v = (t < NBINS) ? cnt[t] : 0;
    scanbuf[t] = v;
    __syncthreads();
    for (int off = 1; off < 1024; off <<= 1) {
        int add = (t >= off) ? scanbuf[t - off] : 0;
        __syncthreads();
        scanbuf[t] += add;
        __syncthreads();
    }
    if (t < NBINS) ex[t] = scanbuf[t] - v;
    __syncthreads();

    // stage in bin-sorted order
    #pragma unroll
    for (int i = 0; i < EPT; ++i)
        if (bn[i] >= 0) stage[ex[bn[i]] + rk[i]] = pk[i];
    __syncthreads();

    // coalesced write-out: 16-lane group per bin
    const int g   = t >> 4;    // 0..63
    const int l16 = t & 15;
    for (int b = g; b < NBINS; b += 64) {
        int c = cnt[b];
        if (c == 0) continue;
        int lb = ex[b];
        int gb = gbase[b];
        int cmax = (b + 1) * CAP - gb;   // capacity guard
        if (cmax < 0) cmax = 0;
        if (c > cmax) c = cmax;
        for (int j = l16; j < c; j += 16)
            bedges[gb + j] = stage[lb + j];
    }
}

// ---------------------------------------------------------------------------
// Pass 2 (fused): per-bucket LDS sort, then software-pipelined gather.
// (unchanged from round 13)
// ---------------------------------------------------------------------------
__global__ __launch_bounds__(512) void sort_gather_kernel(
    const int* __restrict__ cursor, const unsigned* __restrict__ bedges,
    const unsigned short* __restrict__ yb,
    float* __restrict__ out, int n_nodes)
{
    __shared__ unsigned ent[CAP];      // 16 KB raw entries
    __shared__ unsigned sorted[CAP];   // 16 KB src ids sorted by local dst
    __shared__ int cnt[NPB];
    __shared__ int ex[NPB];
    __shared__ int cur[NPB];

    const int b = blockIdx.x;
    const int t = threadIdx.x;
    const int start = b * CAP;
    int n = cursor[b] - start;
    if (n > CAP) n = CAP;
    if (n < 0) n = 0;

    if (t < NPB) { cnt[t] = 0; cur[t] = 0; }
    __syncthreads();

    for (int i = t; i < n; i += 512) {
        unsigned e = bedges[start + i];
        ent[i] = e;
        atomicAdd(&cnt[e & (NPB - 1)], 1);
    }
    __syncthreads();

    if (t < NPB) ex[t] = cnt[t];
    __syncthreads();
    for (int off = 1; off < NPB; off <<= 1) {
        int add = 0;
        if (t < NPB && t >= off) add = ex[t - off];
        __syncthreads();
        if (t < NPB) ex[t] += add;
        __syncthreads();
    }
    if (t < NPB) ex[t] -= cnt[t];
    __syncthreads();

    for (int i = t; i < n; i += 512) {
        unsigned e = ent[i];
        int bin = (int)(e & (NPB - 1));
        int r = atomicAdd(&cur[bin], 1);
        sorted[ex[bin] + r] = e >> LOG_NPB;
    }
    __syncthreads();

    // ---- pipelined gather phase ----
    const int wv   = t >> 6;      // wave 0..7
    const int lane = t & 63;
    const int slot = lane >> 3;   // 0..7: edge slot
    const int li   = lane & 7;    // dims li*4..li*4+3

    int ln   = wv;
    int node = b * NPB + ln;
    if (node >= n_nodes) return;

    int st = ex[ln];
    int d  = cnt[ln];
    int s[4];
    #pragma unroll
    for (int k = 0; k < 4; ++k) {
        int e = slot + 8 * k;
        int idx = (e < d) ? e : (d > 0 ? d - 1 : 0);
        s[k] = (int)sorted[(d > 0 ? st : 0) + idx];
    }
    float4 o = make_float4(0.f, 0.f, 0.f, 0.f);
    if (slot == 0) o = ((const float4*)(out + ((size_t)node << 5)))[li];

    while (true) {
        ushort4 u[4];
        #pragma unroll
        for (int k = 0; k < 4; ++k) {
            if (8 * k < d)    // wave-uniform
                u[k] = *(const ushort4*)(yb + ((size_t)s[k] << 5) + (li << 2));
        }

        const int ln_n   = ln + 8;
        const int node_n = node + 8;
        const bool have_n = (ln_n < NPB) && (node_n < n_nodes);
        int st_n = 0, d_n = 0;
        int sn[4];
        float4 o_n = make_float4(0.f, 0.f, 0.f, 0.f);
        if (have_n) {
            st_n = ex[ln_n];
            d_n  = cnt[ln_n];
            #pragma unroll
            for (int k = 0; k < 4; ++k) {
                int e = slot + 8 * k;
                int idx = (e < d_n) ? e : (d_n > 0 ? d_n - 1 : 0);
                sn[k] = (int)sorted[(d_n > 0 ? st_n : 0) + idx];
            }
            if (slot == 0) o_n = ((const float4*)(out + ((size_t)node_n << 5)))[li];
        }

        float a0 = 0.f, a1 = 0.f, a2 = 0.f, a3 = 0.f;
        #pragma unroll
        for (int k = 0; k < 4; ++k) {
            if (8 * k < d) {   // wave-uniform
                const bool v = (slot + 8 * k) < d;
                a0 += v ? __uint_as_float((unsigned)u[k].x << 16) : 0.f;
                a1 += v ? __uint_as_float((unsigned)u[k].y << 16) : 0.f;
                a2 += v ? __uint_as_float((unsigned)u[k].z << 16) : 0.f;
                a3 += v ? __uint_as_float((unsigned)u[k].w << 16) : 0.f;
            }
        }
        for (int e0 = 32 + slot; e0 < d; e0 += 8) {
            int ss = (int)sorted[st + e0];
            ushort4 uu = *(const ushort4*)(yb + ((size_t)ss << 5) + (li << 2));
            a0 += __uint_as_float((unsigned)uu.x << 16);
            a1 += __uint_as_float((unsigned)uu.y << 16);
            a2 += __uint_as_float((unsigned)uu.z << 16);
            a3 += __uint_as_float((unsigned)uu.w << 16);
        }

        #pragma unroll
        for (int m = 8; m < 64; m <<= 1) {
            a0 += __shfl_xor(a0, m);
            a1 += __shfl_xor(a1, m);
            a2 += __shfl_xor(a2, m);
            a3 += __shfl_xor(a3, m);
        }

        if (slot == 0 && d > 0) {
            float4 w;
            w.x = o.x + a0; w.y = o.y + a1; w.z = o.z + a2; w.w = o.w + a3;
            ((float4*)(out + ((size_t)node << 5)))[li] = w;
        }

        if (!have_n) break;
        ln = ln_n; node = node_n; st = st_n; d = d_n;
        s[0] = sn[0]; s[1] = sn[1]; s[2] = sn[2]; s[3] = sn[3];
        o = o_n;
    }
}

extern "C" void kernel_launch(void* const* d_in, const int* in_sizes, int n_in,
                              void* d_out, int out_size, void* d_ws, size_t ws_size,
                              hipStream_t stream) {
    const float* x  = (const float*)d_in[0];
    const float* W1 = (const float*)d_in[1];
    const float* W2 = (const float*)d_in[2];
    const float* b2 = (const float*)d_in[3];
    const int*   ei = (const int*)d_in[4];

    const int n_nodes = in_sizes[0] / DIM;   // 100000
    const int n_edges = in_sizes[4] / 2;     // 1,600,000
    const int* src = ei;
    const int* dst = ei + n_edges;
    float* out = (float*)d_out;

    const int nb = (n_nodes + NPB - 1) / NPB;    // 782

    char* basep = (char*)d_ws;
    size_t off = 0;
    auto alloc = [&](size_t bytes) {
        char* p = basep + off;
        off = (off + bytes + 255) & ~(size_t)255;
        return p;
    };
    unsigned* y32    = (unsigned*)alloc((size_t)n_nodes * DIM * sizeof(unsigned short));
    int*      cursor = (int*)     alloc((size_t)nb * sizeof(int));
    unsigned* bedges = (unsigned*)alloc((size_t)nb * CAP * sizeof(unsigned));
    (void)ws_size;

    fused_lin_kernel<<<1024, 256, 0, stream>>>(x, W1, W2, b2, out, y32, cursor, nb, n_nodes);
    bucket_scatter_kernel<<<(n_edges + EPB - 1) / EPB, 1024, 0, stream>>>(src, dst, cursor, bedges, n_edges);
    sort_gather_kernel<<<nb, 512, 0, stream>>>(cursor, bedges, (const unsigned short*)y32, out, n_nodes);
}

// Round 17
// 79.628 us; speedup vs baseline: 1.1192x; 1.0325x over previous
//
#include <hip/hip_runtime.h>
#include <hip/hip_bf16.h>

#define DIM 32
#define LOG_NPB 7
#define NPB 128              // nodes per bucket
#define CAP 4096             // edge capacity per bucket (avg ~2046)
#define NBINS 800            // >= ceil(100000/128)=782
#define EPB 16384            // edges per scatter block
#define EPT 16               // edges per thread in scatter (EPB/1024)

// ---------------------------------------------------------------------------
// Kernel 1: out = x @ W2^T + b2 (fp32) ;  y = x @ W1^T (bf16 packed).
// Weights held in REGISTERS per lane (lane owns output column c = t&31):
// w{1,2}r[q] = W{1,2}[c][4q..4q+3]  (torch Linear: y[c] = sum_k x[k]*W[c][k]).
// Replaces 96 scalar ds_reads/thread/tile with 8 broadcast ds_read_b128.
// Block 0 also inits bucket cursors (absolute: cursor[b] = b*CAP).
// ---------------------------------------------------------------------------
__global__ __launch_bounds__(256) void fused_lin_kernel(
    const float* __restrict__ x,
    const float* __restrict__ W1,
    const float* __restrict__ W2,
    const float* __restrict__ b2,
    float* __restrict__ out,
    unsigned* __restrict__ y32,
    int* __restrict__ cursor, int nb,
    int n_nodes)
{
    __shared__ float xs[8][DIM];

    const int t = threadIdx.x;

    if (blockIdx.x == 0) {
        for (int i = t; i < nb; i += 256) cursor[i] = i * CAP;
    }

    const int r = t >> 5;   // row within 8-row tile
    const int c = t & 31;   // output column

    // per-lane weight rows (row c of W = column c of W^T), 64 VGPRs
    float4 w1r[8], w2r[8];
    #pragma unroll
    for (int q = 0; q < 8; ++q) {
        w1r[q] = *(const float4*)(W1 + c * DIM + q * 4);
        w2r[q] = *(const float4*)(W2 + c * DIM + q * 4);
    }
    const float bias = b2[c];

    const int ntiles = (n_nodes + 7) >> 3;

    for (int tile = blockIdx.x; tile < ntiles; tile += gridDim.x) {
        const int row = tile * 8 + r;
        __syncthreads();
        if (row < n_nodes) xs[r][c] = x[(long)row * DIM + c];
        __syncthreads();
        if (row < n_nodes) {
            const float4* xr = (const float4*)xs[r];
            float a2 = bias;
            float a1 = 0.0f;
            #pragma unroll
            for (int q = 0; q < 8; ++q) {
                float4 xv = xr[q];   // broadcast b128 (2 addrs/wave, conflict-free)
                a2 += xv.x * w2r[q].x + xv.y * w2r[q].y + xv.z * w2r[q].z + xv.w * w2r[q].w;
                a1 += xv.x * w1r[q].x + xv.y * w1r[q].y + xv.z * w1r[q].z + xv.w * w1r[q].w;
            }
            out[(long)row * DIM + c] = a2;
            float hi = __shfl_down(a1, 1);
            if ((c & 1) == 0) {
                __hip_bfloat16 blo = __float2bfloat16(a1);
                __hip_bfloat16 bhi = __float2bfloat16(hi);
                unsigned pack = ((unsigned)(*(unsigned short*)&bhi) << 16)
                              | (unsigned)(*(unsigned short*)&blo);
                y32[(size_t)row * 16 + (c >> 1)] = pack;
            }
        }
    }
}

// ---------------------------------------------------------------------------
// Pass 1: bucket scatter (round-13 variant: 98 fat blocks, rank merged
// into histogram atomic).
// ---------------------------------------------------------------------------
__global__ __launch_bounds__(1024) void bucket_scatter_kernel(
    const int* __restrict__ src, const int* __restrict__ dst,
    int* __restrict__ cursor, unsigned* __restrict__ bedges, int nE)
{
    __shared__ int cnt[NBINS];
    __shared__ int base[NBINS];

    const int t = threadIdx.x;
    const long blockStart = (long)blockIdx.x * EPB;

    for (int i = t; i < NBINS; i += 1024) cnt[i] = 0;
    __syncthreads();

    int es[EPT], ed[EPT], rk[EPT];
    #pragma unroll
    for (int i = 0; i < EPT; ++i) {
        long e = blockStart + (long)i * 1024 + t;
        if (e < nE) { es[i] = src[e]; ed[i] = dst[e]; }
        else        { es[i] = -1;     ed[i] = 0;      }
    }
    #pragma unroll
    for (int i = 0; i < EPT; ++i) {
        if (es[i] >= 0) rk[i] = atomicAdd(&cnt[ed[i] >> LOG_NPB], 1);
    }
    __syncthreads();

    for (int i = t; i < NBINS; i += 1024) {
        int c = cnt[i];
        if (c > 0) base[i] = atomicAdd(&cursor[i], c);
    }
    __syncthreads();

    #pragma unroll
    for (int i = 0; i < EPT; ++i) {
        if (es[i] >= 0) {
            int b = ed[i] >> LOG_NPB;
            int p = base[b] + rk[i];
            if (p < (b + 1) * CAP)
                bedges[p] = ((unsigned)es[i] << LOG_NPB) | (unsigned)(ed[i] & (NPB - 1));
        }
    }
}

// ---------------------------------------------------------------------------
// Pass 2 (fused): per-bucket LDS sort, then software-pipelined gather.
// (unchanged from round 13)
// ---------------------------------------------------------------------------
__global__ __launch_bounds__(512) void sort_gather_kernel(
    const int* __restrict__ cursor, const unsigned* __restrict__ bedges,
    const unsigned short* __restrict__ yb,
    float* __restrict__ out, int n_nodes)
{
    __shared__ unsigned ent[CAP];      // 16 KB raw entries
    __shared__ unsigned sorted[CAP];   // 16 KB src ids sorted by local dst
    __shared__ int cnt[NPB];
    __shared__ int ex[NPB];
    __shared__ int cur[NPB];

    const int b = blockIdx.x;
    const int t = threadIdx.x;
    const int start = b * CAP;
    int n = cursor[b] - start;
    if (n > CAP) n = CAP;
    if (n < 0) n = 0;

    if (t < NPB) { cnt[t] = 0; cur[t] = 0; }
    __syncthreads();

    for (int i = t; i < n; i += 512) {
        unsigned e = bedges[start + i];
        ent[i] = e;
        atomicAdd(&cnt[e & (NPB - 1)], 1);
    }
    __syncthreads();

    if (t < NPB) ex[t] = cnt[t];
    __syncthreads();
    for (int off = 1; off < NPB; off <<= 1) {
        int add = 0;
        if (t < NPB && t >= off) add = ex[t - off];
        __syncthreads();
        if (t < NPB) ex[t] += add;
        __syncthreads();
    }
    if (t < NPB) ex[t] -= cnt[t];
    __syncthreads();

    for (int i = t; i < n; i += 512) {
        unsigned e = ent[i];
        int bin = (int)(e & (NPB - 1));
        int r = atomicAdd(&cur[bin], 1);
        sorted[ex[bin] + r] = e >> LOG_NPB;
    }
    __syncthreads();

    // ---- pipelined gather phase ----
    const int wv   = t >> 6;      // wave 0..7
    const int lane = t & 63;
    const int slot = lane >> 3;   // 0..7: edge slot
    const int li   = lane & 7;    // dims li*4..li*4+3

    int ln   = wv;
    int node = b * NPB + ln;
    if (node >= n_nodes) return;

    int st = ex[ln];
    int d  = cnt[ln];
    int s[4];
    #pragma unroll
    for (int k = 0; k < 4; ++k) {
        int e = slot + 8 * k;
        int idx = (e < d) ? e : (d > 0 ? d - 1 : 0);
        s[k] = (int)sorted[(d > 0 ? st : 0) + idx];
    }
    float4 o = make_float4(0.f, 0.f, 0.f, 0.f);
    if (slot == 0) o = ((const float4*)(out + ((size_t)node << 5)))[li];

    while (true) {
        ushort4 u[4];
        #pragma unroll
        for (int k = 0; k < 4; ++k) {
            if (8 * k < d)    // wave-uniform
                u[k] = *(const ushort4*)(yb + ((size_t)s[k] << 5) + (li << 2));
        }

        const int ln_n   = ln + 8;
        const int node_n = node + 8;
        const bool have_n = (ln_n < NPB) && (node_n < n_nodes);
        int st_n = 0, d_n = 0;
        int sn[4];
        float4 o_n = make_float4(0.f, 0.f, 0.f, 0.f);
        if (have_n) {
            st_n = ex[ln_n];
            d_n  = cnt[ln_n];
            #pragma unroll
            for (int k = 0; k < 4; ++k) {
                int e = slot + 8 * k;
                int idx = (e < d_n) ? e : (d_n > 0 ? d_n - 1 : 0);
                sn[k] = (int)sorted[(d_n > 0 ? st_n : 0) + idx];
            }
            if (slot == 0) o_n = ((const float4*)(out + ((size_t)node_n << 5)))[li];
        }

        float a0 = 0.f, a1 = 0.f, a2 = 0.f, a3 = 0.f;
        #pragma unroll
        for (int k = 0; k < 4; ++k) {
            if (8 * k < d) {   // wave-uniform
                const bool v = (slot + 8 * k) < d;
                a0 += v ? __uint_as_float((unsigned)u[k].x << 16) : 0.f;
                a1 += v ? __uint_as_float((unsigned)u[k].y << 16) : 0.f;
                a2 += v ? __uint_as_float((unsigned)u[k].z << 16) : 0.f;
                a3 += v ? __uint_as_float((unsigned)u[k].w << 16) : 0.f;
            }
        }
        for (int e0 = 32 + slot; e0 < d; e0 += 8) {
            int ss = (int)sorted[st + e0];
            ushort4 uu = *(const ushort4*)(yb + ((size_t)ss << 5) + (li << 2));
            a0 += __uint_as_float((unsigned)uu.x << 16);
            a1 += __uint_as_float((unsigned)uu.y << 16);
            a2 += __uint_as_float((unsigned)uu.z << 16);
            a3 += __uint_as_float((unsigned)uu.w << 16);
        }

        #pragma unroll
        for (int m = 8; m < 64; m <<= 1) {
            a0 += __shfl_xor(a0, m);
            a1 += __shfl_xor(a1, m);
            a2 += __shfl_xor(a2, m);
            a3 += __shfl_xor(a3, m);
        }

        if (slot == 0 && d > 0) {
            float4 w;
            w.x = o.x + a0; w.y = o.y + a1; w.z = o.z + a2; w.w = o.w + a3;
            ((float4*)(out + ((size_t)node << 5)))[li] = w;
        }

        if (!have_n) break;
        ln = ln_n; node = node_n; st = st_n; d = d_n;
        s[0] = sn[0]; s[1] = sn[1]; s[2] = sn[2]; s[3] = sn[3];
        o = o_n;
    }
}

extern "C" void kernel_launch(void* const* d_in, const int* in_sizes, int n_in,
                              void* d_out, int out_size, void* d_ws, size_t ws_size,
                              hipStream_t stream) {
    const float* x  = (const float*)d_in[0];
    const float* W1 = (const float*)d_in[1];
    const float* W2 = (const float*)d_in[2];
    const float* b2 = (const float*)d_in[3];
    const int*   ei = (const int*)d_in[4];

    const int n_nodes = in_sizes[0] / DIM;   // 100000
    const int n_edges = in_sizes[4] / 2;     // 1,600,000
    const int* src = ei;
    const int* dst = ei + n_edges;
    float* out = (float*)d_out;

    const int nb = (n_nodes + NPB - 1) / NPB;    // 782

    char* basep = (char*)d_ws;
    size_t off = 0;
    auto alloc = [&](size_t bytes) {
        char* p = basep + off;
        off = (off + bytes + 255) & ~(size_t)255;
        return p;
    };
    unsigned* y32    = (unsigned*)alloc((size_t)n_nodes * DIM * sizeof(unsigned short));
    int*      cursor = (int*)     alloc((size_t)nb * sizeof(int));
    unsigned* bedges = (unsigned*)alloc((size_t)nb * CAP * sizeof(unsigned));
    (void)ws_size;

    fused_lin_kernel<<<1024, 256, 0, stream>>>(x, W1, W2, b2, out, y32, cursor, nb, n_nodes);
    bucket_scatter_kernel<<<(n_edges + EPB - 1) / EPB, 1024, 0, stream>>>(src, dst, cursor, bedges, n_edges);
    sort_gather_kernel<<<nb, 512, 0, stream>>>(cursor, bedges, (const unsigned short*)y32, out, n_nodes);
}